// Round 4
// baseline (2777.519 us; speedup 1.0000x reference)
//
#include <hip/hip_runtime.h>
#include <hip/hip_bf16.h>
#include <math.h>

#define M_TOT 4096
#define K_TOT 1024
#define V_TOT 32000

typedef short short8 __attribute__((ext_vector_type(8)));
typedef float f32x4 __attribute__((ext_vector_type(4)));

__device__ __forceinline__ void gload_lds16(const void* g, void* l) {
  __builtin_amdgcn_global_load_lds(
      (const __attribute__((address_space(1))) void*)g,
      (__attribute__((address_space(3))) void*)l, 16, 0, 0);
}

__device__ __forceinline__ unsigned short f2bf(float f) {
  unsigned int u = __builtin_bit_cast(unsigned int, f);
  unsigned int lsb = (u >> 16) & 1u;
  u += 0x7fffu + lsb;
  return (unsigned short)(u >> 16);
}

__device__ __forceinline__ float sani(float v) {
  return (v != v) ? 0.0f : fminf(fmaxf(v, -1e4f), 1e4f);
}

__global__ void prep_h(const float* __restrict__ h, unsigned short* __restrict__ hbf,
                       float* __restrict__ h0) {
  int m = blockIdx.x;
  int t = threadIdx.x;
  const float* row = h + (long)m * (K_TOT + 1);
  if (t == 0) h0[m] = sani(row[0]);
  unsigned short* dst = hbf + (long)m * K_TOT;
#pragma unroll
  for (int j = 0; j < 4; ++j) {
    int idx = t * 4 + j;
    dst[idx] = f2bf(sani(row[1 + idx]));
  }
}

__global__ void prep_w(const float* __restrict__ w, unsigned short* __restrict__ wbf,
                       float* __restrict__ wtime) {
  __shared__ float red[4];
  __shared__ float r_sh;
  int v = blockIdx.x;
  int t = threadIdx.x;
  const float* row = w + (long)v * K_TOT;
  float4 x = *(const float4*)(row + t * 4);
  float s = x.x * x.x + x.y * x.y + x.z * x.z + x.w * x.w;
#pragma unroll
  for (int off = 32; off > 0; off >>= 1) s += __shfl_down(s, off);
  int lane = t & 63, wv = t >> 6;
  if (lane == 0) red[wv] = s;
  __syncthreads();
  if (t == 0) {
    float tot = red[0] + red[1] + red[2] + red[3];
    float norm = sqrtf(tot);
    float r = (norm > 1e-7f) ? (sinhf(norm) / fmaxf(norm, 1e-7f)) : 1.0f;
    r_sh = r;
    wtime[v] = coshf(norm);
  }
  __syncthreads();
  float r = r_sh;
  ushort4 pack;
  pack.x = f2bf(r * x.x);
  pack.y = f2bf(r * x.y);
  pack.z = f2bf(r * x.z);
  pack.w = f2bf(r * x.w);
  *(ushort4*)(wbf + (long)v * K_TOT + t * 4) = pack;
}

// ---------------- 256x256 tile, BK=32, 8-wave phase-interleaved GEMM --------
// LDS layout (bytes): off = d*32768 + mat*16384 + row*64 + chunk*16
// Bank base of a 64B row repeats every 2 rows, so the XOR swizzle must use
// row bits 1-2: slot chunk c holds global k-chunk c ^ ((row>>1)&3). gload_lds
// writes LINEARLY (thread t -> row=t/4, slot c=t%3), so the global SOURCE is
// pre-swizzled: thread t loads global chunk (t&3) ^ ((t>>3)&3). ds_read
// applies the same XOR: slot chunk = fq ^ ((fr>>1)&3). This gives exactly
// 2 dwords/bank per quarter-wave b128 (minimal). (rule #21: both sides)
#define BAR __builtin_amdgcn_s_barrier()
#define LGKM0 asm volatile("s_waitcnt lgkmcnt(0)" ::: "memory")
#define VM2 asm volatile("s_waitcnt vmcnt(2)" ::: "memory")
#define RD8(off) (*(const short8*)(smem + (off)))
#define DSA(d, mb)                                     \
  {                                                    \
    _Pragma("unroll") for (int i = 0; i < 4; ++i)      \
        af[i] = RD8(a_rd + (d)*32768 + ((mb) + i) * 1024); \
  }
#define DSB(d)                                         \
  {                                                    \
    _Pragma("unroll") for (int i = 0; i < 4; ++i)      \
        bf[i] = RD8(b_rd + (d)*32768 + i * 1024);      \
  }
#define MF16(mb)                                                              \
  {                                                                           \
    __builtin_amdgcn_s_setprio(1);                                            \
    _Pragma("unroll") for (int i = 0; i < 4; ++i)                             \
        _Pragma("unroll") for (int n = 0; n < 4; ++n) acc[(mb) + i][n] =      \
            __builtin_amdgcn_mfma_f32_16x16x32_bf16(af[i], bf[n],             \
                                                    acc[(mb) + i][n], 0, 0, 0); \
    __builtin_amdgcn_s_setprio(0);                                            \
  }

__global__ __launch_bounds__(512, 4) void gemm_geo(
    const unsigned short* __restrict__ hbf, const unsigned short* __restrict__ wbf,
    const float* __restrict__ h0, const float* __restrict__ wtime,
    const float* __restrict__ ls, float* __restrict__ out) {
  __shared__ __align__(16) char smem[65536];

  const int t = threadIdx.x;
  const int wave = t >> 6, lane = t & 63;
  const int fr = lane & 15, fq = lane >> 4;
  const int wm = wave >> 2, wn = wave & 3;  // 2 (M) x 4 (N) wave grid

  // XCD-bijective swizzle: 2000 blocks, 250/XCD; 16 consecutive blocks on an
  // XCD share one 512KB B-panel (L2-resident reuse window).
  int bid = blockIdx.x;
  int swz = (bid & 7) * 250 + (bid >> 3);
  int tile_v = swz >> 4;   // 0..124
  int tile_m = swz & 15;   // 0..15
  int row0 = tile_m * 256;
  int col0 = tile_v * 256;

  // ds_read lane bases (bytes)
  const int sw = (fq ^ ((fr >> 1) & 3)) * 16;
  const int a_rd = (wm * 128 + fr) * 64 + sw;           // + d*32768 + mi*1024
  const int b_rd = 16384 + (wn * 64 + fr) * 64 + sw;    // + d*32768 + ni*1024

  // stage: thread t covers (row=t>>2, slot chunk=t&3); global chunk
  // pre-swizzled so slot c holds global chunk c ^ ((row>>1)&3)
  const int cc = (t & 3) ^ ((t >> 3) & 3);
  const unsigned short* pA = hbf + (long)(row0 + (t >> 2)) * K_TOT + cc * 8;
  const unsigned short* pB = wbf + (long)(col0 + (t >> 2)) * K_TOT + cc * 8;
  const int dst_w = wave * 1024;  // wave-uniform; HW adds lane*16

  auto STAGE_A = [&](int kt, int h, int d) {
    gload_lds16(pA + (long)h * 131072 + kt * 32,
                smem + d * 32768 + h * 8192 + dst_w);
  };
  auto STAGE_B = [&](int kt, int h, int d) {
    gload_lds16(pB + (long)h * 131072 + kt * 32,
                smem + d * 32768 + 16384 + h * 8192 + dst_w);
  };

  f32x4 acc[8][4];
#pragma unroll
  for (int i = 0; i < 8; ++i)
#pragma unroll
    for (int j = 0; j < 4; ++j) acc[i][j] = (f32x4)(0.0f);
  short8 af[4], bf[4];

  // prologue: K-tile0 (A,B) -> dbuf0; B of K-tile1 -> dbuf1 (steady-state
  // stagger). vmcnt(2): A0,B0 landed, B1 may fly.
  STAGE_A(0, 0, 0); STAGE_A(0, 1, 0);
  STAGE_B(0, 0, 0); STAGE_B(0, 1, 0);
  STAGE_B(1, 0, 1); STAGE_B(1, 1, 1);
  VM2;
  BAR;

#pragma unroll 1
  for (int I = 0; I < 16; ++I) {
    int sA1 = 2 * I + 1;                          // always valid (<=31)
    int s2 = (2 * I + 2 < 32) ? 2 * I + 2 : 31;   // clamped redundant stage
    int sB3 = (2 * I + 3 < 32) ? 2 * I + 3 : 31;
    // P1: compute kt=2I (dbuf0) m0-3; stage A(2I+1)->dbuf1
    DSA(0, 0); DSB(0);
    STAGE_A(sA1, 0, 1); STAGE_A(sA1, 1, 1);
    BAR; LGKM0;
    MF16(0);
    BAR;
    // P2: m4-7; stage B(2I+2)->dbuf0; vmcnt(2) => A(2I+1) landed
    DSA(0, 4);
    STAGE_B(s2, 0, 0); STAGE_B(s2, 1, 0);
    VM2;
    BAR; LGKM0;
    MF16(4);
    BAR;
    // P3: compute kt=2I+1 (dbuf1) m0-3; stage A(2I+2)->dbuf0
    DSA(1, 0); DSB(1);
    STAGE_A(s2, 0, 0); STAGE_A(s2, 1, 0);
    BAR; LGKM0;
    MF16(0);
    BAR;
    // P4: m4-7; stage B(2I+3)->dbuf1; vmcnt(2) => A(2I+2),B(2I+2) landed
    DSA(1, 4);
    STAGE_B(sB3, 0, 1); STAGE_B(sB3, 1, 1);
    VM2;
    BAR; LGKM0;
    MF16(4);
    BAR;
  }

  // fused epilogue: x = h0*w_time - dot; d2 = safe_acosh(x)^2; out = -tau*d2
  float ntau = -fminf(fmaxf(ls[0], 0.01f), 2.5f);
  const float LN2 = 0.69314718055994531f;
  float wt[4];
#pragma unroll
  for (int ni = 0; ni < 4; ++ni) wt[ni] = wtime[col0 + wn * 64 + ni * 16 + fr];
#pragma unroll
  for (int mi = 0; mi < 8; ++mi) {
#pragma unroll
    for (int j = 0; j < 4; ++j) {
      int m = row0 + wm * 128 + mi * 16 + fq * 4 + j;
      float h0v = h0[m];
      float* orow = out + (long)m * V_TOT + col0 + wn * 64 + fr;
#pragma unroll
      for (int ni = 0; ni < 4; ++ni) {
        float dot = acc[mi][ni][j];
        float x = fmaf(h0v, wt[ni], -dot);
        float xm1 = fmaxf(x - 1.0f, 0.0f);
        float arg = fmaxf(fmaf(x, x, -1.0f), 0.0f);
        float lg2 = __builtin_amdgcn_logf(x + __builtin_amdgcn_sqrtf(arg));
        float dex = LN2 * lg2;
        float d2_exact = dex * dex;
        float ts = fmaf(xm1, -1.0f / 12.0f, 1.0f);
        float d2_tay = 2.0f * xm1 * ts * ts;
        float d2 = (xm1 < 1e-3f) ? d2_tay : d2_exact;
        __builtin_nontemporal_store(ntau * d2, &orow[ni * 16]);
      }
    }
  }
}

extern "C" void kernel_launch(void* const* d_in, const int* in_sizes, int n_in,
                              void* d_out, int out_size, void* d_ws, size_t ws_size,
                              hipStream_t stream) {
  const float* h = (const float*)d_in[0];   // [2,2048,1025]
  const float* w = (const float*)d_in[1];   // [32000,1024]
  const float* ls = (const float*)d_in[2];  // scalar
  float* out = (float*)d_out;               // [2,2048,32000] fp32

  char* ws = (char*)d_ws;
  unsigned short* wbf = (unsigned short*)ws;                  // 65,536,000 B
  unsigned short* hbf = (unsigned short*)(ws + 65536000);     // 8,388,608 B
  float* wtime = (float*)(ws + 65536000 + 8388608);           // 128,000 B
  float* h0 = (float*)(ws + 65536000 + 8388608 + 128000);     // 16,384 B

  prep_h<<<M_TOT, 256, 0, stream>>>(h, hbf, h0);
  prep_w<<<V_TOT, 256, 0, stream>>>(w, wbf, wtime);
  gemm_geo<<<2000, 512, 0, stream>>>(hbf, wbf, h0, wtime, ls, out);
}

// Round 5
// 382.140 us; speedup vs baseline: 7.2683x; 7.2683x over previous
//
#include <hip/hip_runtime.h>
#include <hip/hip_bf16.h>
#include <math.h>

#define M_TOT 4096
#define K_TOT 1024
#define V_TOT 32000

typedef short short8 __attribute__((ext_vector_type(8)));
typedef float f32x4 __attribute__((ext_vector_type(4)));

__device__ __forceinline__ void gload_lds16(const void* g, void* l) {
  __builtin_amdgcn_global_load_lds(
      (const __attribute__((address_space(1))) void*)g,
      (__attribute__((address_space(3))) void*)l, 16, 0, 0);
}

__device__ __forceinline__ unsigned short f2bf(float f) {
  unsigned int u = __builtin_bit_cast(unsigned int, f);
  unsigned int lsb = (u >> 16) & 1u;
  u += 0x7fffu + lsb;
  return (unsigned short)(u >> 16);
}

__device__ __forceinline__ float sani(float v) {
  return (v != v) ? 0.0f : fminf(fmaxf(v, -1e4f), 1e4f);
}

__global__ void prep_h(const float* __restrict__ h, unsigned short* __restrict__ hbf,
                       float* __restrict__ h0) {
  int m = blockIdx.x;
  int t = threadIdx.x;
  const float* row = h + (long)m * (K_TOT + 1);
  if (t == 0) h0[m] = sani(row[0]);
  unsigned short* dst = hbf + (long)m * K_TOT;
#pragma unroll
  for (int j = 0; j < 4; ++j) {
    int idx = t * 4 + j;
    dst[idx] = f2bf(sani(row[1 + idx]));
  }
}

__global__ void prep_w(const float* __restrict__ w, unsigned short* __restrict__ wbf,
                       float* __restrict__ wtime) {
  __shared__ float red[4];
  __shared__ float r_sh;
  int v = blockIdx.x;
  int t = threadIdx.x;
  const float* row = w + (long)v * K_TOT;
  float4 x = *(const float4*)(row + t * 4);
  float s = x.x * x.x + x.y * x.y + x.z * x.z + x.w * x.w;
#pragma unroll
  for (int off = 32; off > 0; off >>= 1) s += __shfl_down(s, off);
  int lane = t & 63, wv = t >> 6;
  if (lane == 0) red[wv] = s;
  __syncthreads();
  if (t == 0) {
    float tot = red[0] + red[1] + red[2] + red[3];
    float norm = sqrtf(tot);
    float r = (norm > 1e-7f) ? (sinhf(norm) / fmaxf(norm, 1e-7f)) : 1.0f;
    r_sh = r;
    wtime[v] = coshf(norm);
  }
  __syncthreads();
  float r = r_sh;
  ushort4 pack;
  pack.x = f2bf(r * x.x);
  pack.y = f2bf(r * x.y);
  pack.z = f2bf(r * x.z);
  pack.w = f2bf(r * x.w);
  *(ushort4*)(wbf + (long)v * K_TOT + t * 4) = pack;
}

// ---------------- 256x256 tile, BK=32, 8-wave phase-interleaved GEMM --------
// LDS layout (bytes): off = d*32768 + mat*16384 + row*64 + chunk*16
// Bank base of a 64B row repeats every 2 rows, so the XOR swizzle uses row
// bits 1-2: slot chunk c holds global k-chunk c ^ ((row>>1)&3). gload_lds
// writes LINEARLY (thread t -> row=t/4, slot c=t%4), so the global SOURCE is
// pre-swizzled: thread t loads global chunk (t&3) ^ ((t>>3)&3). ds_read
// applies the same XOR: slot chunk = fq ^ ((fr>>1)&3). Verified: this gives
// SQ_LDS_BANK_CONFLICT == 0 (round-4 counters). (rule #21: both sides)
//
// NOTE on launch bounds: (512,4) capped VGPRs at 64 -> acc[8][4] (128 regs)
// spilled to scratch -> 13.9 GB HBM traffic, 2.8 ms (round 4). Keep (512,2):
// 1 block/CU, no spill; the phase schedule (not multi-block occupancy) is
// what hides the barriers (m201 runs 62% MfmaUtil at 1 block/CU).
#define BAR __builtin_amdgcn_s_barrier()
#define LGKM0 asm volatile("s_waitcnt lgkmcnt(0)" ::: "memory")
#define VM2 asm volatile("s_waitcnt vmcnt(2)" ::: "memory")
#define RD8(off) (*(const short8*)(smem + (off)))
#define DSA(d, mb)                                     \
  {                                                    \
    _Pragma("unroll") for (int i = 0; i < 4; ++i)      \
        af[i] = RD8(a_rd + (d)*32768 + ((mb) + i) * 1024); \
  }
#define DSB(d)                                         \
  {                                                    \
    _Pragma("unroll") for (int i = 0; i < 4; ++i)      \
        bf[i] = RD8(b_rd + (d)*32768 + i * 1024);      \
  }
#define MF16(mb)                                                              \
  {                                                                           \
    __builtin_amdgcn_s_setprio(1);                                            \
    _Pragma("unroll") for (int i = 0; i < 4; ++i)                             \
        _Pragma("unroll") for (int n = 0; n < 4; ++n) acc[(mb) + i][n] =      \
            __builtin_amdgcn_mfma_f32_16x16x32_bf16(af[i], bf[n],             \
                                                    acc[(mb) + i][n], 0, 0, 0); \
    __builtin_amdgcn_s_setprio(0);                                            \
  }

__global__ __launch_bounds__(512, 2) void gemm_geo(
    const unsigned short* __restrict__ hbf, const unsigned short* __restrict__ wbf,
    const float* __restrict__ h0, const float* __restrict__ wtime,
    const float* __restrict__ ls, float* __restrict__ out) {
  __shared__ __align__(16) char smem[65536];

  const int t = threadIdx.x;
  const int wave = t >> 6, lane = t & 63;
  const int fr = lane & 15, fq = lane >> 4;
  const int wm = wave >> 2, wn = wave & 3;  // 2 (M) x 4 (N) wave grid

  // XCD-bijective swizzle: 2000 blocks, 250/XCD; 16 consecutive blocks on an
  // XCD share one 512KB B-panel (L2-resident reuse window).
  int bid = blockIdx.x;
  int swz = (bid & 7) * 250 + (bid >> 3);
  int tile_v = swz >> 4;   // 0..124
  int tile_m = swz & 15;   // 0..15
  int row0 = tile_m * 256;
  int col0 = tile_v * 256;

  // ds_read lane bases (bytes)
  const int sw = (fq ^ ((fr >> 1) & 3)) * 16;
  const int a_rd = (wm * 128 + fr) * 64 + sw;           // + d*32768 + mi*1024
  const int b_rd = 16384 + (wn * 64 + fr) * 64 + sw;    // + d*32768 + ni*1024

  // stage: thread t covers (row=t>>2, slot chunk=t&3); global chunk
  // pre-swizzled so slot c holds global chunk c ^ ((row>>1)&3)
  const int cc = (t & 3) ^ ((t >> 3) & 3);
  const unsigned short* pA = hbf + (long)(row0 + (t >> 2)) * K_TOT + cc * 8;
  const unsigned short* pB = wbf + (long)(col0 + (t >> 2)) * K_TOT + cc * 8;
  const int dst_w = wave * 1024;  // wave-uniform; HW adds lane*16

  auto STAGE_A = [&](int kt, int h, int d) {
    gload_lds16(pA + (long)h * 131072 + kt * 32,
                smem + d * 32768 + h * 8192 + dst_w);
  };
  auto STAGE_B = [&](int kt, int h, int d) {
    gload_lds16(pB + (long)h * 131072 + kt * 32,
                smem + d * 32768 + 16384 + h * 8192 + dst_w);
  };

  f32x4 acc[8][4];
#pragma unroll
  for (int i = 0; i < 8; ++i)
#pragma unroll
    for (int j = 0; j < 4; ++j) acc[i][j] = (f32x4)(0.0f);
  short8 af[4], bf[4];

  // prologue: K-tile0 (A,B) -> dbuf0; B of K-tile1 -> dbuf1 (steady-state
  // stagger). vmcnt(2): A0,B0 landed, B1 may fly.
  STAGE_A(0, 0, 0); STAGE_A(0, 1, 0);
  STAGE_B(0, 0, 0); STAGE_B(0, 1, 0);
  STAGE_B(1, 0, 1); STAGE_B(1, 1, 1);
  VM2;
  BAR;

#pragma unroll 1
  for (int I = 0; I < 16; ++I) {
    int sA1 = 2 * I + 1;                          // always valid (<=31)
    int s2 = (2 * I + 2 < 32) ? 2 * I + 2 : 31;   // clamped redundant stage
    int sB3 = (2 * I + 3 < 32) ? 2 * I + 3 : 31;
    // P1: compute kt=2I (dbuf0) m0-3; stage A(2I+1)->dbuf1
    DSA(0, 0); DSB(0);
    STAGE_A(sA1, 0, 1); STAGE_A(sA1, 1, 1);
    BAR; LGKM0;
    MF16(0);
    BAR;
    // P2: m4-7; stage B(2I+2)->dbuf0; vmcnt(2) => A(2I+1) landed
    DSA(0, 4);
    STAGE_B(s2, 0, 0); STAGE_B(s2, 1, 0);
    VM2;
    BAR; LGKM0;
    MF16(4);
    BAR;
    // P3: compute kt=2I+1 (dbuf1) m0-3; stage A(2I+2)->dbuf0
    DSA(1, 0); DSB(1);
    STAGE_A(s2, 0, 0); STAGE_A(s2, 1, 0);
    BAR; LGKM0;
    MF16(0);
    BAR;
    // P4: m4-7; stage B(2I+3)->dbuf1; vmcnt(2) => B(2I+2),A(2I+2) landed
    DSA(1, 4);
    STAGE_B(sB3, 0, 1); STAGE_B(sB3, 1, 1);
    VM2;
    BAR; LGKM0;
    MF16(4);
    BAR;
  }

  // fused epilogue: x = h0*w_time - dot; d2 = safe_acosh(x)^2; out = -tau*d2
  float ntau = -fminf(fmaxf(ls[0], 0.01f), 2.5f);
  const float LN2 = 0.69314718055994531f;
  float wt[4];
#pragma unroll
  for (int ni = 0; ni < 4; ++ni) wt[ni] = wtime[col0 + wn * 64 + ni * 16 + fr];
#pragma unroll
  for (int mi = 0; mi < 8; ++mi) {
#pragma unroll
    for (int j = 0; j < 4; ++j) {
      int m = row0 + wm * 128 + mi * 16 + fq * 4 + j;
      float h0v = h0[m];
      float* orow = out + (long)m * V_TOT + col0 + wn * 64 + fr;
#pragma unroll
      for (int ni = 0; ni < 4; ++ni) {
        float dot = acc[mi][ni][j];
        float x = fmaf(h0v, wt[ni], -dot);
        float xm1 = fmaxf(x - 1.0f, 0.0f);
        float arg = fmaxf(fmaf(x, x, -1.0f), 0.0f);
        float lg2 = __builtin_amdgcn_logf(x + __builtin_amdgcn_sqrtf(arg));
        float dex = LN2 * lg2;
        float d2_exact = dex * dex;
        float ts = fmaf(xm1, -1.0f / 12.0f, 1.0f);
        float d2_tay = 2.0f * xm1 * ts * ts;
        float d2 = (xm1 < 1e-3f) ? d2_tay : d2_exact;
        __builtin_nontemporal_store(ntau * d2, &orow[ni * 16]);
      }
    }
  }
}

extern "C" void kernel_launch(void* const* d_in, const int* in_sizes, int n_in,
                              void* d_out, int out_size, void* d_ws, size_t ws_size,
                              hipStream_t stream) {
  const float* h = (const float*)d_in[0];   // [2,2048,1025]
  const float* w = (const float*)d_in[1];   // [32000,1024]
  const float* ls = (const float*)d_in[2];  // scalar
  float* out = (float*)d_out;               // [2,2048,32000] fp32

  char* ws = (char*)d_ws;
  unsigned short* wbf = (unsigned short*)ws;                  // 65,536,000 B
  unsigned short* hbf = (unsigned short*)(ws + 65536000);     // 8,388,608 B
  float* wtime = (float*)(ws + 65536000 + 8388608);           // 128,000 B
  float* h0 = (float*)(ws + 65536000 + 8388608 + 128000);     // 16,384 B

  prep_h<<<M_TOT, 256, 0, stream>>>(h, hbf, h0);
  prep_w<<<V_TOT, 256, 0, stream>>>(w, wbf, wtime);
  gemm_geo<<<2000, 512, 0, stream>>>(hbf, wbf, h0, wtime, ls, out);
}